// Round 5
// baseline (565.902 us; speedup 1.0000x reference)
//
#include <hip/hip_runtime.h>
#include <hip/hip_bf16.h>

#define NTOK 4096
#define DDIM 1024
#define NEXP 8
#define FDIM 4096
#define MAXTILES 40

typedef __attribute__((ext_vector_type(4))) float f32x4;
typedef __attribute__((ext_vector_type(8))) short bf16x8;
typedef __attribute__((ext_vector_type(8))) unsigned short u16x8;

#define GLDS(g, l) __builtin_amdgcn_global_load_lds( \
    (const __attribute__((address_space(1))) unsigned int*)(g), \
    (__attribute__((address_space(3))) unsigned int*)(l), 16, 0, 0)

// ---------------- route: no global atomics. Writes xs (bf16), amax[], partial[256][16] ----
__global__ __launch_bounds__(256) void route_kernel(
    const float* __restrict__ x,         // [NTOK, D]
    const float* __restrict__ w_switch,  // [D, E]
    const float* __restrict__ b_switch,  // [E]
    __hip_bfloat16* __restrict__ xs,     // [NTOK, D]
    int* __restrict__ amax_arr,          // [NTOK]
    float* __restrict__ partial)         // [256][16]: 0..7 prob sums, 8..15 counts
{
    const int tid = threadIdx.x;
    const int wave = tid >> 6, lane = tid & 63;
    __shared__ float pr[4][16];

    float wacc[16];
#pragma unroll
    for (int j = 0; j < 16; j++) wacc[j] = 0.0f;

    for (int i = 0; i < 4; i++) {
        const int n = blockIdx.x * 16 + wave * 4 + i;
        const float4* xr = (const float4*)(x + (size_t)n * DDIM);
        float4 xv[4];
#pragma unroll
        for (int j = 0; j < 4; j++) xv[j] = xr[lane + j * 64];

        float acc[NEXP];
#pragma unroll
        for (int e = 0; e < NEXP; e++) acc[e] = 0.0f;
#pragma unroll
        for (int j = 0; j < 4; j++) {
            const int dbase = (lane + j * 64) * 4;
#pragma unroll
            for (int c = 0; c < 4; c++) {
                const float4* wr = (const float4*)(w_switch + (size_t)(dbase + c) * NEXP);
                float4 w0 = wr[0], w1 = wr[1];
                float xvc = ((const float*)&xv[j])[c];
                acc[0] += xvc * w0.x; acc[1] += xvc * w0.y;
                acc[2] += xvc * w0.z; acc[3] += xvc * w0.w;
                acc[4] += xvc * w1.x; acc[5] += xvc * w1.y;
                acc[6] += xvc * w1.z; acc[7] += xvc * w1.w;
            }
        }
#pragma unroll
        for (int e = 0; e < NEXP; e++) {
            float v = acc[e];
#pragma unroll
            for (int off = 32; off > 0; off >>= 1) v += __shfl_xor(v, off, 64);
            acc[e] = v;
        }
        float mx = -1e30f;
#pragma unroll
        for (int e = 0; e < NEXP; e++) {
            acc[e] += b_switch[e];
            mx = fmaxf(mx, acc[e]);
        }
        float sum = 0.0f;
#pragma unroll
        for (int e = 0; e < NEXP; e++) { acc[e] = __expf(acc[e] - mx); sum += acc[e]; }
        float inv = 1.0f / sum;
        float pmax = -1.0f; int amax = 0;
#pragma unroll
        for (int e = 0; e < NEXP; e++) {
            float p = acc[e] * inv;
            acc[e] = p;
            if (p > pmax) { pmax = p; amax = e; }
        }
#pragma unroll
        for (int e = 0; e < NEXP; e++) {
            wacc[e] += acc[e];
            wacc[8 + e] += (amax == e) ? 1.0f : 0.0f;
        }
        if (lane == 0) amax_arr[n] = amax;
#pragma unroll
        for (int j = 0; j < 4; j++) {
            ushort4 pk;
            __hip_bfloat16* pp = (__hip_bfloat16*)&pk;
            pp[0] = __float2bfloat16(xv[j].x * pmax);
            pp[1] = __float2bfloat16(xv[j].y * pmax);
            pp[2] = __float2bfloat16(xv[j].z * pmax);
            pp[3] = __float2bfloat16(xv[j].w * pmax);
            *(ushort4*)(xs + (size_t)n * DDIM + (lane + j * 64) * 4) = pk;
        }
    }
    if (lane == 0) {
#pragma unroll
        for (int j = 0; j < 16; j++) pr[wave][j] = wacc[j];
    }
    __syncthreads();
    if (tid < 16)
        partial[blockIdx.x * 16 + tid] = pr[0][tid] + pr[1][tid] + pr[2][tid] + pr[3][tid];
}

// ---------------- bucket: per-expert token lists, ballot-aggregated, LDS counter ----------
__global__ __launch_bounds__(1024) void bucket_kernel(
    const int* __restrict__ amax_arr, int* __restrict__ bucket, int* __restrict__ ecnt)
{
    const int e = blockIdx.x;
    __shared__ int ctr;
    if (threadIdx.x == 0) ctr = 0;
    __syncthreads();
    const int lane = threadIdx.x & 63;
    for (int c = 0; c < NTOK; c += 1024) {
        int t = c + threadIdx.x;
        bool my = (amax_arr[t] == e);
        unsigned long long mask = __ballot(my);
        int cnt = __popcll(mask);
        int base = 0;
        if (lane == 0 && cnt) base = atomicAdd(&ctr, cnt);
        base = __shfl(base, 0, 64);
        if (my) {
            int rank = __popcll(mask & ((1ull << lane) - 1ull));
            bucket[e * NTOK + base + rank] = t;
        }
    }
    __syncthreads();
    if (threadIdx.x == 0) ecnt[e] = ctr;
}

// ---------------- finalize + m-tile table ----------------
__global__ __launch_bounds__(256) void finalize_table_kernel(
    const float* __restrict__ partial, const int* __restrict__ ecnt,
    float* __restrict__ out_tail, int* __restrict__ table)
{
    __shared__ float red[16][16];
    const int j = threadIdx.x & 15, g = threadIdx.x >> 4;
    float s = 0.0f;
    for (int k = 0; k < 16; k++) s += partial[(size_t)(g + k * 16) * 16 + j];
    red[g][j] = s;
    __syncthreads();
    if (threadIdx.x < 16) {
        float t = 0.0f;
        for (int k = 0; k < 16; k++) t += red[k][threadIdx.x];
        int dst = (threadIdx.x < 8) ? (8 + threadIdx.x) : (threadIdx.x - 8);
        out_tail[dst] = t;
    }
    if (threadIdx.x == 16) out_tail[16] = 0.0f;  // n_dropped
    if (threadIdx.x == 0) {
        int idx = 0;
        for (int e = 0; e < NEXP; e++) {
            int cnt = ecnt[e];
            for (int m0 = 0; m0 < cnt; m0 += 128) table[idx++] = (e << 16) | m0;
        }
        for (; idx < MAXTILES; idx++) table[idx] = -1;
    }
}

// ---------------- init_out: out[t][:] = b2[amax[t]][:] (bias pre-fill for atomic GEMM2) ----
__global__ __launch_bounds__(256) void init_out_kernel(
    const float* __restrict__ b2, const int* __restrict__ amax_arr,
    float* __restrict__ out)
{
    const int t = blockIdx.x;
    const int e = amax_arr[t];
    const float4* br = (const float4*)(b2 + (size_t)e * DDIM);
    ((float4*)(out + (size_t)t * DDIM))[threadIdx.x] = br[threadIdx.x];
}

// ---------------- grouped GEMM, fused B fp32->bf16 transpose, double-buffered LDS -------
// B is the ORIGINAL fp32 weight [E][K][NN] (K contraction rows, NN output cols).
// MODE 0: h = bf16(relu(acc + bias)).   MODE 1: unsafeAtomicAdd fp32 (bias pre-filled).
template <int MODE, int K, int NN, int KS>
__device__ __forceinline__ void gemm_body(
    const __hip_bfloat16* __restrict__ A,
    const float* __restrict__ Bw,
    const float* __restrict__ bias,
    const int* __restrict__ bucket,
    const int* __restrict__ ecnt,
    const int* __restrict__ table,
    void* __restrict__ Out)
{
    const int entry = table[blockIdx.x];
    if (entry < 0) return;
    const int e = entry >> 16;
    const int m0 = entry & 0xffff;
    const int cnt = ecnt[e];
    const int n0 = blockIdx.y * 128;
    constexpr int KB = K / KS;
    constexpr int ITERS = KB / 32;
    const int kbase = KB * blockIdx.z;

    __shared__ __align__(16) __hip_bfloat16 Asm[2][128 * 32];
    __shared__ __align__(16) __hip_bfloat16 Bsm[2][128 * 32];
    __shared__ int toks[128];

    const int tid = threadIdx.x;
    if (tid < 128) {
        int rr = m0 + tid;
        toks[tid] = bucket[e * NTOK + (rr < cnt ? rr : cnt - 1)];
    }
    __syncthreads();

    const int wave = tid >> 6, lane = tid & 63;
    const int r = lane & 15, kq = lane >> 4;
    const int g0 = 2 * wave, g1 = 2 * wave + 1;

    const __hip_bfloat16* pA0 = A + (size_t)toks[g0 * 16 + r] * K + kbase + kq * 8;
    const __hip_bfloat16* pA1 = A + (size_t)toks[g1 * 16 + r] * K + kbase + kq * 8;

    // B staging: thread covers 4 consecutive k rows (krow..krow+3) x 4 consecutive n (nc..nc+3)
    const int krow = (tid >> 5) * 4;   // 0,4,...,28
    const int nc = (tid & 31) * 4;     // 0,4,...,124  (lanes 0..31 = 512B contiguous)
    const float* Bg = Bw + ((size_t)e * K + kbase) * NN + n0 + nc;
    // LDS fragment-order address: group (nc>>4)*1024 + (kq*16 + nr)*16 + (k&7)*2
    const int boff = (nc >> 4) * 1024 + ((krow >> 3) * 16 + (nc & 15)) * 16 + (krow & 7) * 2;

    const int wm = wave & 1, wn = wave >> 1;
    f32x4 acc[4][4];
#pragma unroll
    for (int t = 0; t < 4; t++)
#pragma unroll
        for (int u = 0; u < 4; u++) acc[t][u] = (f32x4){0.f, 0.f, 0.f, 0.f};

    float4 bcur[4], bnxt[4];
#pragma unroll
    for (int j = 0; j < 4; j++)
        bcur[j] = *(const float4*)&Bg[(size_t)(krow + j) * NN];

    GLDS(pA0, (char*)Asm[0] + g0 * 1024);
    GLDS(pA1, (char*)Asm[0] + g1 * 1024);
    pA0 += 32; pA1 += 32;

    {   // convert+scatter tile0 B (4 x ds_write_b64, <=2-way bank aliasing)
        char* bb = (char*)Bsm[0] + boff;
#pragma unroll
        for (int i2 = 0; i2 < 4; i2++) {
            ushort4 pk;
            __hip_bfloat16* pp = (__hip_bfloat16*)&pk;
            pp[0] = __float2bfloat16(((float*)&bcur[0])[i2]);
            pp[1] = __float2bfloat16(((float*)&bcur[1])[i2]);
            pp[2] = __float2bfloat16(((float*)&bcur[2])[i2]);
            pp[3] = __float2bfloat16(((float*)&bcur[3])[i2]);
            *(ushort4*)(bb + i2 * 16) = pk;
        }
    }
    if (ITERS > 1) {
#pragma unroll
        for (int j = 0; j < 4; j++)
            bnxt[j] = *(const float4*)&Bg[(size_t)(32 + krow + j) * NN];
    }
    __syncthreads();

    for (int it = 0; it < ITERS; it++) {
        const int cur = it & 1, nxt = cur ^ 1;
        if (it + 1 < ITERS) {
            // stage tile it+1: A via direct-to-LDS DMA, B from prefetched regs
            GLDS(pA0, (char*)Asm[nxt] + g0 * 1024);
            GLDS(pA1, (char*)Asm[nxt] + g1 * 1024);
            pA0 += 32; pA1 += 32;
            char* bb = (char*)Bsm[nxt] + boff;
#pragma unroll
            for (int i2 = 0; i2 < 4; i2++) {
                ushort4 pk;
                __hip_bfloat16* pp = (__hip_bfloat16*)&pk;
                pp[0] = __float2bfloat16(((float*)&bnxt[0])[i2]);
                pp[1] = __float2bfloat16(((float*)&bnxt[1])[i2]);
                pp[2] = __float2bfloat16(((float*)&bnxt[2])[i2]);
                pp[3] = __float2bfloat16(((float*)&bnxt[3])[i2]);
                *(ushort4*)(bb + i2 * 16) = pk;
            }
        }
        if (it + 2 < ITERS) {
            // issue B loads for tile it+2; consumed next iteration (overlap = MFMA section)
#pragma unroll
            for (int j = 0; j < 4; j++)
                bnxt[j] = *(const float4*)&Bg[(size_t)((it + 2) * 32 + krow + j) * NN];
        }
        bf16x8 a[4], b[4];
#pragma unroll
        for (int t = 0; t < 4; t++)
            a[t] = *(const bf16x8*)((const char*)Asm[cur] + (wm * 4 + t) * 1024 + lane * 16);
#pragma unroll
        for (int u = 0; u < 4; u++)
            b[u] = *(const bf16x8*)((const char*)Bsm[cur] + (wn * 4 + u) * 1024 + lane * 16);
#pragma unroll
        for (int t = 0; t < 4; t++)
#pragma unroll
            for (int u = 0; u < 4; u++)
                acc[t][u] = __builtin_amdgcn_mfma_f32_16x16x32_bf16(a[t], b[u], acc[t][u], 0, 0, 0);
        __syncthreads();   // single barrier per iteration (double-buffered LDS)
    }

    const int quad = lane >> 4, l15 = lane & 15;
    float bv[4];
#pragma unroll
    for (int u = 0; u < 4; u++)
        bv[u] = (MODE == 0) ? bias[(size_t)e * NN + n0 + wn * 64 + u * 16 + l15] : 0.0f;
#pragma unroll
    for (int t = 0; t < 4; t++) {
#pragma unroll
        for (int rr = 0; rr < 4; rr++) {
            int row = wm * 64 + t * 16 + quad * 4 + rr;
            if (m0 + row < cnt) {
                int tok = toks[row];
#pragma unroll
                for (int u = 0; u < 4; u++) {
                    int col = n0 + wn * 64 + u * 16 + l15;
                    float v = acc[t][u][rr] + bv[u];
                    if (MODE == 0) {
                        v = fmaxf(v, 0.0f);
                        ((__hip_bfloat16*)Out)[(size_t)tok * NN + col] = __float2bfloat16(v);
                    } else {
                        unsafeAtomicAdd(&((float*)Out)[(size_t)tok * NN + col], v);
                    }
                }
            }
        }
    }
}

__global__ __launch_bounds__(256) void gemm_ffn1(
    const __hip_bfloat16* __restrict__ A, const float* __restrict__ Bw,
    const float* __restrict__ bias, const int* __restrict__ bucket,
    const int* __restrict__ ecnt, const int* __restrict__ table, void* __restrict__ Out)
{
    gemm_body<0, DDIM, FDIM, 1>(A, Bw, bias, bucket, ecnt, table, Out);
}

__global__ __launch_bounds__(256) void gemm_ffn2(
    const __hip_bfloat16* __restrict__ A, const float* __restrict__ Bw,
    const float* __restrict__ bias, const int* __restrict__ bucket,
    const int* __restrict__ ecnt, const int* __restrict__ table, void* __restrict__ Out)
{
    gemm_body<1, FDIM, DDIM, 4>(A, Bw, bias, bucket, ecnt, table, Out);
}

extern "C" void kernel_launch(void* const* d_in, const int* in_sizes, int n_in,
                              void* d_out, int out_size, void* d_ws, size_t ws_size,
                              hipStream_t stream) {
    const float* x        = (const float*)d_in[0];
    const float* w_switch = (const float*)d_in[1];
    const float* b_switch = (const float*)d_in[2];
    const float* w1       = (const float*)d_in[3];
    const float* b1       = (const float*)d_in[4];
    const float* w2       = (const float*)d_in[5];
    const float* b2       = (const float*)d_in[6];

    float* out = (float*)d_out;
    float* out_tail = out + (size_t)NTOK * DDIM;

    char* ws = (char*)d_ws;
    __hip_bfloat16* xs = (__hip_bfloat16*)(ws);                        // 8 MB
    __hip_bfloat16* h  = (__hip_bfloat16*)(ws + 8388608ull);           // 32 MB
    int* bucket        = (int*)(ws + 41943040ull);                     // 128 KB
    int* amax_arr      = (int*)(ws + 42074112ull);                     // 16 KB
    float* partial     = (float*)(ws + 42090496ull);                   // 16 KB
    int* ecnt          = (int*)(ws + 42106880ull);                     // 32 B
    int* table         = (int*)(ws + 42106912ull);                     // 160 B

    hipLaunchKernelGGL(route_kernel, dim3(256), dim3(256), 0, stream,
                       x, w_switch, b_switch, xs, amax_arr, partial);
    hipLaunchKernelGGL(bucket_kernel, dim3(NEXP), dim3(1024), 0, stream,
                       amax_arr, bucket, ecnt);
    hipLaunchKernelGGL(finalize_table_kernel, dim3(1), dim3(256), 0, stream,
                       partial, ecnt, out_tail, table);
    hipLaunchKernelGGL(init_out_kernel, dim3(NTOK), dim3(256), 0, stream,
                       b2, amax_arr, out);

    // GEMM1: h = relu(xs @ w1 + b1), w1 fp32 [E,1024,4096] consumed directly
    hipLaunchKernelGGL(gemm_ffn1, dim3(MAXTILES, FDIM / 128), dim3(256), 0, stream,
                       xs, w1, b1, bucket, ecnt, table, (void*)h);

    // GEMM2: out += h @ w2 (bias pre-filled), w2 fp32 [E,4096,1024], split-K=4
    hipLaunchKernelGGL(gemm_ffn2, dim3(MAXTILES, DDIM / 128, 4), dim3(256), 0, stream,
                       h, w2, b2, bucket, ecnt, table, (void*)out);
}